// Round 2
// baseline (97.857 us; speedup 1.0000x reference)
//
#include <hip/hip_runtime.h>

// Butterfly: out = butterfly_mult_untied(twiddle, x) + bias
// x: (32768, 1024) f32; twiddle: (1, 10, 512, 2, 2) f32; bias: (1024,) f32
// Stage idx pairs n with n^(1<<idx); matrix index p = n with bit idx deleted;
// out(n) = t[p][i][i]*v(n) + t[p][i][1-i]*v(n^stride), i = bit idx of n.
//
// Layout: 256 threads, thread owns n = tid*4 + e (e=0..3).
//   stages 0-1: intra-thread; stages 2-7: __shfl_xor (lane bits 0..5);
//   stages 8-9: MERGED into one 4-term combo via LDS (partners tid^64/128/192).
// Twiddle is pre-swapped into (self,partner) form, pinned in VGPRs via asm.

#define RPB 16        // rows per block
#define RB  2         // rows per batch
#define NB  (RPB/RB)  // batches per block

__global__ __launch_bounds__(256, 4)
void butterfly_kernel(const float* __restrict__ x,
                      const float* __restrict__ tw,
                      const float* __restrict__ bias,
                      float* __restrict__ out) {
    __shared__ float4 lds[2][RB][256];
    const int tid = threadIdx.x;
    const int n0 = tid * 4;
    const int rowbase = blockIdx.x * RPB;

    // Issue batch-0 input loads FIRST so their latency overlaps twiddle preload.
    float4 cur[RB];
#pragma unroll
    for (int r = 0; r < RB; ++r)
        cur[r] = *reinterpret_cast<const float4*>(x + (size_t)(rowbase + r) * 1024 + n0);

    // ---- Twiddle preload (once per block) ----
    // Stages 0..7: (self, partner) coefficient per element.
    float twm[8][4], two_[8][4];
#pragma unroll
    for (int idx = 0; idx < 8; ++idx) {
        const int stride = 1 << idx;
#pragma unroll
        for (int e = 0; e < 4; ++e) {
            const int n = n0 + e;
            const int p = ((n >> (idx + 1)) << idx) | (n & (stride - 1));
            const int i = (n >> idx) & 1;
            const float* tp = tw + idx * 2048 + p * 4 + i * 2;  // &t[idx][p][i][0]
            twm[idx][e]  = tp[i];
            two_[idx][e] = tp[1 - i];
        }
    }
    // Stages 8+9 merged: out9(n) = c0*w(n) + c1*w(n^256) + c2*w(n^512) + c3*w(n^768)
    float c0[4], c1[4], c2[4], c3[4];
    {
        const int b8 = (tid >> 6) & 1;   // bit 8 of n
        const int b9 = (tid >> 7) & 1;   // bit 9 of n
#pragma unroll
        for (int e = 0; e < 4; ++e) {
            const int n   = n0 + e;
            const int low = n & 255;
            const int p9  = n & 511;                       // n with bit 9 removed
            const float* t9p = tw + 9 * 2048 + p9 * 4 + b9 * 2;
            const float A = t9p[b9], B = t9p[1 - b9];
            const float* t8a = tw + 8 * 2048 + (( b9      << 8) | low) * 4 + b8 * 2; // p8(n)
            const float* t8b = tw + 8 * 2048 + (((1 - b9) << 8) | low) * 4 + b8 * 2; // p8(n^512)
            c0[e] = A * t8a[b8];
            c1[e] = A * t8a[1 - b8];
            c2[e] = B * t8b[b8];
            c3[e] = B * t8b[1 - b8];
        }
    }
    float4 b4 = *reinterpret_cast<const float4*>(bias + n0);

    // Pin all per-block constants in VGPRs: forbids the compiler from
    // rematerializing these as per-iteration global loads (round-1 failure mode).
#pragma unroll
    for (int idx = 0; idx < 8; ++idx)
#pragma unroll
        for (int e = 0; e < 4; ++e)
            asm volatile("" : "+v"(twm[idx][e]), "+v"(two_[idx][e]));
#pragma unroll
    for (int e = 0; e < 4; ++e)
        asm volatile("" : "+v"(c0[e]), "+v"(c1[e]), "+v"(c2[e]), "+v"(c3[e]));
    asm volatile("" : "+v"(b4.x), "+v"(b4.y), "+v"(b4.z), "+v"(b4.w));

    for (int b = 0; b < NB; ++b) {
        float v[RB][4];
#pragma unroll
        for (int r = 0; r < RB; ++r) {
            v[r][0] = cur[r].x; v[r][1] = cur[r].y; v[r][2] = cur[r].z; v[r][3] = cur[r].w;
        }
        // stage 0 (stride 1): pairs (e0,e1),(e2,e3)
#pragma unroll
        for (int r = 0; r < RB; ++r) {
            float a0 = twm[0][0] * v[r][0] + two_[0][0] * v[r][1];
            float a1 = twm[0][1] * v[r][1] + two_[0][1] * v[r][0];
            float a2 = twm[0][2] * v[r][2] + two_[0][2] * v[r][3];
            float a3 = twm[0][3] * v[r][3] + two_[0][3] * v[r][2];
            v[r][0] = a0; v[r][1] = a1; v[r][2] = a2; v[r][3] = a3;
        }
        // stage 1 (stride 2): pairs (e0,e2),(e1,e3)
#pragma unroll
        for (int r = 0; r < RB; ++r) {
            float a0 = twm[1][0] * v[r][0] + two_[1][0] * v[r][2];
            float a1 = twm[1][1] * v[r][1] + two_[1][1] * v[r][3];
            float a2 = twm[1][2] * v[r][2] + two_[1][2] * v[r][0];
            float a3 = twm[1][3] * v[r][3] + two_[1][3] * v[r][1];
            v[r][0] = a0; v[r][1] = a1; v[r][2] = a2; v[r][3] = a3;
        }
        // stages 2..7: cross-lane via shfl_xor, rows interleaved for ILP
#pragma unroll
        for (int idx = 2; idx < 8; ++idx) {
            const int m = 1 << (idx - 2);
#pragma unroll
            for (int r = 0; r < RB; ++r)
#pragma unroll
                for (int e = 0; e < 4; ++e) {
                    const float o = __shfl_xor(v[r][e], m, 64);
                    v[r][e] = twm[idx][e] * v[r][e] + two_[idx][e] * o;
                }
        }
        // merged stages 8+9: one LDS round-trip, one barrier per batch.
        const int buf = b & 1;
#pragma unroll
        for (int r = 0; r < RB; ++r)
            lds[buf][r][tid] = make_float4(v[r][0], v[r][1], v[r][2], v[r][3]);
        __syncthreads();

        // Prefetch next batch now: no barrier between issue and use, so these
        // loads stay in flight under the tail compute + stores.
        if (b + 1 < NB) {
#pragma unroll
            for (int r = 0; r < RB; ++r)
                cur[r] = *reinterpret_cast<const float4*>(
                    x + (size_t)(rowbase + (b + 1) * RB + r) * 1024 + n0);
        }

#pragma unroll
        for (int r = 0; r < RB; ++r) {
            const float4 o64  = lds[buf][r][tid ^ 64];
            const float4 o128 = lds[buf][r][tid ^ 128];
            const float4 o192 = lds[buf][r][tid ^ 192];
            float4 s;
            s.x = c0[0]*v[r][0] + c1[0]*o64.x + c2[0]*o128.x + c3[0]*o192.x + b4.x;
            s.y = c0[1]*v[r][1] + c1[1]*o64.y + c2[1]*o128.y + c3[1]*o192.y + b4.y;
            s.z = c0[2]*v[r][2] + c1[2]*o64.z + c2[2]*o128.z + c3[2]*o192.z + b4.z;
            s.w = c0[3]*v[r][3] + c1[3]*o64.w + c2[3]*o128.w + c3[3]*o192.w + b4.w;
            *reinterpret_cast<float4*>(out + (size_t)(rowbase + b * RB + r) * 1024 + n0) = s;
        }
        // Double buffer + the one barrier above make the next batch's LDS writes
        // race-free: any thread's write to buf happens after barrier(b+1), which
        // all threads reach only after their reads of buf in batch b.
    }
}

extern "C" void kernel_launch(void* const* d_in, const int* in_sizes, int n_in,
                              void* d_out, int out_size, void* d_ws, size_t ws_size,
                              hipStream_t stream) {
    const float* x    = (const float*)d_in[0];
    const float* tw   = (const float*)d_in[1];
    const float* bias = (const float*)d_in[2];
    float* outp = (float*)d_out;
    dim3 grid(32768 / RPB);   // 2048 blocks
    dim3 block(256);
    hipLaunchKernelGGL(butterfly_kernel, grid, block, 0, stream, x, tw, bias, outp);
}

// Round 3
// 85.252 us; speedup vs baseline: 1.1479x; 1.1479x over previous
//
#include <hip/hip_runtime.h>

// Butterfly: out = butterfly_mult_untied(twiddle, x) + bias
// x: (32768, 1024) f32; twiddle: (1, 10, 512, 2, 2) f32; bias: (1024,) f32
// Stage idx pairs n with n^(1<<idx); matrix index p = n with bit idx deleted;
// out(n) = t[p][i][i]*v(n) + t[p][i][1-i]*v(n^stride), i = bit idx of n.
//
// Layout: 256 threads, thread owns n = tid*4 + e.
//   stages 0-1: intra-thread (bits 0-1)
//   stage 2: lane^1  -> DPP quad_perm [1,0,3,2]          (VALU)
//   stage 3: lane^2  -> DPP quad_perm [2,3,0,1]          (VALU)
//   stage 4: lane^4  -> ds_swizzle xor4 (0x101F)         (LDS pipe)
//   stage 5: lane^8  -> DPP row_ror:8 (== xor8 mod 16)   (VALU)
//   stage 6: lane^16 -> v_permlane16_swap + cndmask      (VALU)
//   stage 7: lane^32 -> v_permlane32_swap + cndmask      (VALU)
//   stages 8-9: merged 4-term combo via one LDS roundtrip + barrier.
// Twiddle pre-swapped to (self,partner) form, pinned in regs via asm.

#define RPB 16        // rows per block
#define RB  2         // rows per batch
#define NB  (RPB/RB)  // batches per block

typedef int v2i __attribute__((ext_vector_type(2)));

template<int CTRL>
__device__ __forceinline__ float dppf(float v) {
    const int i = __float_as_int(v);
    return __int_as_float(__builtin_amdgcn_update_dpp(i, i, CTRL, 0xF, 0xF, true));
}

__device__ __forceinline__ float xor4f(float v) {
    return __int_as_float(__builtin_amdgcn_ds_swizzle(__float_as_int(v), 0x101F));
}

__device__ __forceinline__ float xor16f(float v, bool hi16) {
#if __has_builtin(__builtin_amdgcn_permlane16_swap)
    const int i = __float_as_int(v);
    const v2i p = __builtin_amdgcn_permlane16_swap(i, i, false, false);
    // rows after swap(v,v): p[0]=[v0,v0,v2,v2], p[1]=[v1,v1,v3,v3] -> xor16 = hi16?p[0]:p[1]
    return __int_as_float(hi16 ? p[0] : p[1]);
#else
    return __int_as_float(__builtin_amdgcn_ds_swizzle(__float_as_int(v), 0x401F));
#endif
}

__device__ __forceinline__ float xor32f(float v, bool hi32, int bpaddr) {
#if __has_builtin(__builtin_amdgcn_permlane32_swap)
    const int i = __float_as_int(v);
    const v2i p = __builtin_amdgcn_permlane32_swap(i, i, false, false);
    // p[0]=[v0,v1,v0,v1], p[1]=[v2,v3,v2,v3] -> xor32 = hi32?p[0]:p[1]
    return __int_as_float(hi32 ? p[0] : p[1]);
#else
    return __int_as_float(__builtin_amdgcn_ds_bpermute(bpaddr, __float_as_int(v)));
#endif
}

__global__ __launch_bounds__(256, 4)
void butterfly_kernel(const float* __restrict__ x,
                      const float* __restrict__ tw,
                      const float* __restrict__ bias,
                      float* __restrict__ out) {
    __shared__ float4 lds[2][RB][256];
    const int tid  = threadIdx.x;
    const int lane = tid & 63;
    const bool hi16 = (lane & 16) != 0;
    const bool hi32 = (lane & 32) != 0;
    const int bpaddr = ((lane ^ 32) & 63) << 2;  // fallback bpermute addr
    const int n0 = tid * 4;
    const int rowbase = blockIdx.x * RPB;

    // Issue batch-0 loads first so their latency overlaps the twiddle preload.
    float4 cur[RB];
#pragma unroll
    for (int r = 0; r < RB; ++r)
        cur[r] = *reinterpret_cast<const float4*>(x + (size_t)(rowbase + r) * 1024 + n0);

    // ---- Twiddle preload (once per block), pre-swapped (self, partner) ----
    float twm[8][4], two_[8][4];
#pragma unroll
    for (int idx = 0; idx < 8; ++idx) {
        const int stride = 1 << idx;
#pragma unroll
        for (int e = 0; e < 4; ++e) {
            const int n = n0 + e;
            const int p = ((n >> (idx + 1)) << idx) | (n & (stride - 1));
            const int i = (n >> idx) & 1;
            const float* tp = tw + idx * 2048 + p * 4 + i * 2;
            twm[idx][e]  = tp[i];
            two_[idx][e] = tp[1 - i];
        }
    }
    // Stages 8+9 merged: out(n) = c0*w(n) + c1*w(n^256) + c2*w(n^512) + c3*w(n^768)
    float c0[4], c1[4], c2[4], c3[4];
    {
        const int b8 = (tid >> 6) & 1;
        const int b9 = (tid >> 7) & 1;
#pragma unroll
        for (int e = 0; e < 4; ++e) {
            const int n   = n0 + e;
            const int low = n & 255;
            const int p9  = n & 511;
            const float* t9p = tw + 9 * 2048 + p9 * 4 + b9 * 2;
            const float A = t9p[b9], B = t9p[1 - b9];
            const float* t8a = tw + 8 * 2048 + (( b9      << 8) | low) * 4 + b8 * 2;
            const float* t8b = tw + 8 * 2048 + (((1 - b9) << 8) | low) * 4 + b8 * 2;
            c0[e] = A * t8a[b8];
            c1[e] = A * t8a[1 - b8];
            c2[e] = B * t8b[b8];
            c3[e] = B * t8b[1 - b8];
        }
    }
    float4 b4 = *reinterpret_cast<const float4*>(bias + n0);

    // Pin per-block constants so the compiler can't re-load them per row.
#pragma unroll
    for (int idx = 0; idx < 8; ++idx)
#pragma unroll
        for (int e = 0; e < 4; ++e)
            asm volatile("" : "+v"(twm[idx][e]), "+v"(two_[idx][e]));
#pragma unroll
    for (int e = 0; e < 4; ++e)
        asm volatile("" : "+v"(c0[e]), "+v"(c1[e]), "+v"(c2[e]), "+v"(c3[e]));
    asm volatile("" : "+v"(b4.x), "+v"(b4.y), "+v"(b4.z), "+v"(b4.w));

    for (int b = 0; b < NB; ++b) {
        float v[RB][4];
#pragma unroll
        for (int r = 0; r < RB; ++r) {
            v[r][0] = cur[r].x; v[r][1] = cur[r].y; v[r][2] = cur[r].z; v[r][3] = cur[r].w;
        }
        // stage 0 (stride 1): pairs (e0,e1),(e2,e3)
#pragma unroll
        for (int r = 0; r < RB; ++r) {
            float a0 = twm[0][0] * v[r][0] + two_[0][0] * v[r][1];
            float a1 = twm[0][1] * v[r][1] + two_[0][1] * v[r][0];
            float a2 = twm[0][2] * v[r][2] + two_[0][2] * v[r][3];
            float a3 = twm[0][3] * v[r][3] + two_[0][3] * v[r][2];
            v[r][0] = a0; v[r][1] = a1; v[r][2] = a2; v[r][3] = a3;
        }
        // stage 1 (stride 2): pairs (e0,e2),(e1,e3)
#pragma unroll
        for (int r = 0; r < RB; ++r) {
            float a0 = twm[1][0] * v[r][0] + two_[1][0] * v[r][2];
            float a1 = twm[1][1] * v[r][1] + two_[1][1] * v[r][3];
            float a2 = twm[1][2] * v[r][2] + two_[1][2] * v[r][0];
            float a3 = twm[1][3] * v[r][3] + two_[1][3] * v[r][1];
            v[r][0] = a0; v[r][1] = a1; v[r][2] = a2; v[r][3] = a3;
        }
        // stage 2: lane^1 via DPP quad_perm [1,0,3,2] = 0xB1
#pragma unroll
        for (int r = 0; r < RB; ++r)
#pragma unroll
            for (int e = 0; e < 4; ++e) {
                const float o = dppf<0xB1>(v[r][e]);
                v[r][e] = twm[2][e] * v[r][e] + two_[2][e] * o;
            }
        // stage 3: lane^2 via DPP quad_perm [2,3,0,1] = 0x4E
#pragma unroll
        for (int r = 0; r < RB; ++r)
#pragma unroll
            for (int e = 0; e < 4; ++e) {
                const float o = dppf<0x4E>(v[r][e]);
                v[r][e] = twm[3][e] * v[r][e] + two_[3][e] * o;
            }
        // stage 4: lane^4 via ds_swizzle
#pragma unroll
        for (int r = 0; r < RB; ++r)
#pragma unroll
            for (int e = 0; e < 4; ++e) {
                const float o = xor4f(v[r][e]);
                v[r][e] = twm[4][e] * v[r][e] + two_[4][e] * o;
            }
        // stage 5: lane^8 via DPP row_ror:8 = 0x128 (rotate-by-8 mod 16 == xor8)
#pragma unroll
        for (int r = 0; r < RB; ++r)
#pragma unroll
            for (int e = 0; e < 4; ++e) {
                const float o = dppf<0x128>(v[r][e]);
                v[r][e] = twm[5][e] * v[r][e] + two_[5][e] * o;
            }
        // stage 6: lane^16 via permlane16_swap
#pragma unroll
        for (int r = 0; r < RB; ++r)
#pragma unroll
            for (int e = 0; e < 4; ++e) {
                const float o = xor16f(v[r][e], hi16);
                v[r][e] = twm[6][e] * v[r][e] + two_[6][e] * o;
            }
        // stage 7: lane^32 via permlane32_swap
#pragma unroll
        for (int r = 0; r < RB; ++r)
#pragma unroll
            for (int e = 0; e < 4; ++e) {
                const float o = xor32f(v[r][e], hi32, bpaddr);
                v[r][e] = twm[7][e] * v[r][e] + two_[7][e] * o;
            }
        // merged stages 8+9: one LDS roundtrip, one barrier per batch.
        const int buf = b & 1;
#pragma unroll
        for (int r = 0; r < RB; ++r)
            lds[buf][r][tid] = make_float4(v[r][0], v[r][1], v[r][2], v[r][3]);
        __syncthreads();

        // Prefetch next batch: stays in flight until consumed (no barrier between).
        if (b + 1 < NB) {
#pragma unroll
            for (int r = 0; r < RB; ++r)
                cur[r] = *reinterpret_cast<const float4*>(
                    x + (size_t)(rowbase + (b + 1) * RB + r) * 1024 + n0);
        }

#pragma unroll
        for (int r = 0; r < RB; ++r) {
            const float4 o64  = lds[buf][r][tid ^ 64];
            const float4 o128 = lds[buf][r][tid ^ 128];
            const float4 o192 = lds[buf][r][tid ^ 192];
            float4 s;
            s.x = c0[0]*v[r][0] + c1[0]*o64.x + c2[0]*o128.x + c3[0]*o192.x + b4.x;
            s.y = c0[1]*v[r][1] + c1[1]*o64.y + c2[1]*o128.y + c3[1]*o192.y + b4.y;
            s.z = c0[2]*v[r][2] + c1[2]*o64.z + c2[2]*o128.z + c3[2]*o192.z + b4.z;
            s.w = c0[3]*v[r][3] + c1[3]*o64.w + c2[3]*o128.w + c3[3]*o192.w + b4.w;
            *reinterpret_cast<float4*>(out + (size_t)(rowbase + b * RB + r) * 1024 + n0) = s;
        }
        // Double buffer + one barrier/batch: every thread's read of buf precedes
        // its next write of buf (separated by the following batch's barrier).
    }
}

extern "C" void kernel_launch(void* const* d_in, const int* in_sizes, int n_in,
                              void* d_out, int out_size, void* d_ws, size_t ws_size,
                              hipStream_t stream) {
    const float* x    = (const float*)d_in[0];
    const float* tw   = (const float*)d_in[1];
    const float* bias = (const float*)d_in[2];
    float* outp = (float*)d_out;
    dim3 grid(32768 / RPB);   // 2048 blocks
    dim3 block(256);
    hipLaunchKernelGGL(butterfly_kernel, grid, block, 0, stream, x, tw, bias, outp);
}